// Round 7
// baseline (229.195 us; speedup 1.0000x reference)
//
#include <hip/hip_runtime.h>
#include <math.h>

// Problem constants: B=8, T=16, P=197, C=1024, R=8
#define BB 8
#define TT 16
#define PP 197
#define CC 1024
#define RR 8
#define NSEQ  (BB * PP)          // 1576 LSTM sequences
#define NROWS (BB * TT * PP)     // 25216 independent rows
#define TP    (TT * PP)          // 3152
#define LORA_SCALE 2.0f          // alpha/rank = 16/8

// Intermediate (masked down-projection, t-major) in a module global.
// Fully rewritten by k_down every iteration before k_lstm_up reads it.
__device__ float g_red[TT * NSEQ * RR];   // 0.8 MB, L2-resident

__device__ __forceinline__ float sigf(float x) {
    x = fminf(fmaxf(x, -30.f), 30.f);
    return 1.0f / (1.0f + __expf(-x));
}
__device__ __forceinline__ float tanh_fast(float x) {
    x = fminf(fmaxf(x, -15.f), 15.f);
    float e = __expf(-2.0f * x);
    return (1.0f - e) / (1.0f + e);
}
__device__ __forceinline__ float dot4(const float4 a, const float4 b) {
    return a.x * b.x + a.y * b.y + a.z * b.z + a.w * b.w;
}

// ---------------------------------------------------------------------------
// K1: LoRA down (verbatim R1 structure -- harness-verified there).
// 1576 blocks x 512 thr (8 waves), 2 rows/wave. dw staged once into 32 KB
// LDS; coalesced float4 row loads; butterfly reduce; masked 32B store.
// R6 post-mortem: the fused kernel ran its memory phases at ~2 blocks/CU
// with a ~1/3 memory duty cycle (84us for 153MB). This kernel has no LSTM
// serialization and ~24 waves/CU -> read-BW-bound.
// ---------------------------------------------------------------------------
__global__ __launch_bounds__(512, 4) void k_down(const float* __restrict__ hs,
                                                 const float* __restrict__ dw,
                                                 const float* __restrict__ fm) {
    __shared__ float4 w_lds[2048];          // dw as float4: 8*1024/4 = 32 KB
    const int tid = threadIdx.x;
#pragma unroll
    for (int j = tid; j < 2048; j += 512) w_lds[j] = ((const float4*)dw)[j];
    __syncthreads();

    const int lane = tid & 63;
    const int wv   = blockIdx.x * 8 + (tid >> 6);
    const int row0 = wv * 2;                 // 12608 waves * 2 = 25216 rows

    float4 xr[2][4];
#pragma unroll
    for (int i = 0; i < 2; ++i) {
        const float* bp = hs + (size_t)(row0 + i) * CC;
#pragma unroll
        for (int k = 0; k < 4; ++k)
            xr[i][k] = *(const float4*)(bp + k * 256 + lane * 4);
    }

    float acc[2][8];
#pragma unroll
    for (int i = 0; i < 2; ++i)
#pragma unroll
        for (int r = 0; r < 8; ++r) acc[i][r] = 0.f;

#pragma unroll
    for (int r = 0; r < 8; ++r)
#pragma unroll
        for (int k = 0; k < 4; ++k) {
            const float4 w = w_lds[r * 256 + k * 64 + lane];   // stride-1: conflict-free
            acc[0][r] += dot4(xr[0][k], w);
            acc[1][r] += dot4(xr[1][k], w);
        }

#pragma unroll
    for (int d = 32; d >= 1; d >>= 1)
#pragma unroll
        for (int i = 0; i < 2; ++i)
#pragma unroll
            for (int r = 0; r < 8; ++r)
                acc[i][r] += __shfl_xor(acc[i][r], d, 64);

    if (lane == 0) {
#pragma unroll
        for (int i = 0; i < 2; ++i) {
            const int row = row0 + i;
            const int b = row / TP;
            const int rem = row - b * TP;
            const int t = rem / PP;
            const int p = rem - t * PP;
            const float m = fm[b * TT + t];
            float* op = g_red + ((size_t)t * NSEQ + b * PP + p) * RR;
            *(float4*)op       = make_float4(acc[i][0] * m, acc[i][1] * m,
                                             acc[i][2] * m, acc[i][3] * m);
            *(float4*)(op + 4) = make_float4(acc[i][4] * m, acc[i][5] * m,
                                             acc[i][6] * m, acc[i][7] * m);
        }
    }
}

// ---------------------------------------------------------------------------
// K2: LSTM + LoRA up, one 256-thr block per sequence. 1 KB LDS, no 32 KB
// weight stage -> residency is VGPR/thread-limited (~6 blocks/CU), so the
// ~1.3us serial LSTM head of each block hides under neighbor blocks' write
// phases. Phase 2 code is R6-verified; phase 3 is R4's global-up streaming
// (L1/L2-resident 32 KB) with R6's dot structure -- both harness-verified.
// ---------------------------------------------------------------------------
__global__ __launch_bounds__(256, 2) void k_lstm_up(const float* __restrict__ w_ih,
                                                    const float* __restrict__ w_hh,
                                                    const float* __restrict__ b_ih,
                                                    const float* __restrict__ b_hh,
                                                    const float* __restrict__ fm,
                                                    const float* __restrict__ up,
                                                    float* __restrict__ out) {
    __shared__ float red_lds[TT][RR];   // masked down-projection (from g_red)
    __shared__ float h_lds[TT][RR];     // masked+scaled hidden states

    const int tid  = threadIdx.x;
    const int lane = tid & 63;
    const int wv   = tid >> 6;          // 0..3
    const int seq  = blockIdx.x;
    const int b    = seq / PP;
    const int p    = seq - b * PP;

    // ---- Stage this sequence's x: 16 t x 2 float4, one load per low lane ----
    if (tid < 32) {
        const int t = tid >> 1, half = tid & 1;
        *(float4*)&red_lds[t][half * 4] =
            *(const float4*)(g_red + ((size_t)t * NSEQ + seq) * RR + half * 4);
    }
    __syncthreads();

    // ---- Phase 2: LSTM on wave 0; lane idx = gate*8 + rank (R6-verified) ----
    if (wv == 0) {
        const int idx = lane & 31;          // lanes 32..63 mirror 0..31 (harmless)
        const int r   = idx & 7;
        const bool isG = (idx >> 3) == 2;   // gate order i,f,g,o; 'g' uses tanh
        float wr[8], whv[8];
        {
            const float* wip = w_ih + idx * 8;
            float4 a = *(const float4*)wip, b4 = *(const float4*)(wip + 4);
            wr[0] = a.x;  wr[1] = a.y;  wr[2] = a.z;  wr[3] = a.w;
            wr[4] = b4.x; wr[5] = b4.y; wr[6] = b4.z; wr[7] = b4.w;
            const float* whp = w_hh + idx * 8;
            float4 c4 = *(const float4*)whp, d4 = *(const float4*)(whp + 4);
            whv[0] = c4.x; whv[1] = c4.y; whv[2] = c4.z; whv[3] = c4.w;
            whv[4] = d4.x; whv[5] = d4.y; whv[6] = d4.z; whv[7] = d4.w;
        }
        const float bias = b_ih[idx] + b_hh[idx];

        float h = 0.f, c = 0.f;
#pragma unroll
        for (int t = 0; t < TT; ++t) {
            const float4 x0 = *(const float4*)&red_lds[t][0];   // broadcast read
            const float4 x1 = *(const float4*)&red_lds[t][4];
            const float xs[8] = {x0.x, x0.y, x0.z, x0.w, x1.x, x1.y, x1.z, x1.w};
            float gv = bias;
#pragma unroll
            for (int j = 0; j < 8; ++j) gv += wr[j] * xs[j];     // off-chain
#pragma unroll
            for (int j = 0; j < 8; ++j) gv += whv[j] * __shfl(h, j, 64);  // h chain
            const float sg = sigf(gv);
            const float tg = tanh_fast(gv);
            const float a  = isG ? tg : sg;                      // this lane's gate act
            const float fa = __shfl(a,  8 + r, 64);              // f-act of rank r
            const float ga = __shfl(a, 16 + r, 64);              // g-act
            const float oa = __shfl(a, 24 + r, 64);              // o-act
            c = fa * c + a * ga;          // valid on lanes idx<8 (a = i-act there)
            h = oa * tanh_fast(c);        // recurrent h is UNmasked (matches ref)
            if (lane < 8) h_lds[t][lane] = h * fm[b * TT + t] * LORA_SCALE;
        }
    }
    __syncthreads();

    // ---- Phase 3: LoRA up. Wave wv: t = 4wv+{0..3}; up streamed from L1/L2 ----
    {
        const int t0 = wv * 4;
        float4 h0[4], h1[4];
#pragma unroll
        for (int i = 0; i < 4; ++i) {
            h0[i] = *(const float4*)&h_lds[t0 + i][0];           // broadcast read
            h1[i] = *(const float4*)&h_lds[t0 + i][4];
        }
        float* obase = out + ((size_t)b * TT * PP + p) * CC;
#pragma unroll
        for (int g4 = 0; g4 < 4; ++g4) {
            // up rows for the 4 consecutive output cols this lane owns: 128B coalesced
            const float* wp = up + (size_t)(g4 * 256 + lane * 4) * RR;
            float4 wA[4], wB[4];
#pragma unroll
            for (int c4 = 0; c4 < 4; ++c4) {
                wA[c4] = *(const float4*)(wp + c4 * RR);
                wB[c4] = *(const float4*)(wp + c4 * RR + 4);
            }
#pragma unroll
            for (int i = 0; i < 4; ++i) {
                float4 o;
                o.x = dot4(h0[i], wA[0]) + dot4(h1[i], wB[0]);
                o.y = dot4(h0[i], wA[1]) + dot4(h1[i], wB[1]);
                o.z = dot4(h0[i], wA[2]) + dot4(h1[i], wB[2]);
                o.w = dot4(h0[i], wA[3]) + dot4(h1[i], wB[3]);
                *(float4*)(obase + (size_t)(t0 + i) * PP * CC + g4 * 256 + lane * 4) = o;
            }
        }
    }
}

extern "C" void kernel_launch(void* const* d_in, const int* in_sizes, int n_in,
                              void* d_out, int out_size, void* d_ws, size_t ws_size,
                              hipStream_t stream) {
    const float* hs  = (const float*)d_in[0];  // (B,T,P,C)
    const float* fm  = (const float*)d_in[2];  // (B,T)
    const float* dw  = (const float*)d_in[3];  // (R,C)
    const float* wih = (const float*)d_in[4];  // (4R,R)
    const float* whh = (const float*)d_in[5];  // (4R,R)
    const float* bih = (const float*)d_in[6];  // (4R,)
    const float* bhh = (const float*)d_in[7];  // (4R,)
    const float* up  = (const float*)d_in[8];  // (C,R)
    float* out = (float*)d_out;

    (void)d_ws; (void)ws_size;   // the 413MB poison fill is unconditional; ws unused

    k_down<<<NSEQ, 512, 0, stream>>>(hs, dw, fm);                          // 1576 blocks
    k_lstm_up<<<NSEQ, 256, 0, stream>>>(wih, whh, bih, bhh, fm, up, out);  // 1576 blocks
}